// Round 4
// baseline (300.522 us; speedup 1.0000x reference)
//
#include <hip/hip_runtime.h>

// GraphGCN via CSR-by-dst + gather aggregation (no fp32 atomics).
// R3: two-level edge bucketing replaces the 8x-reread partitioned fill.
//   bucket_kernel: one pass over (src,dst); per-block LDS count -> global
//     append into 8 per-part pair arrays (coalesced writes, 1 atomic/block/part).
//   degp/fillp: part p handled only by blocks with blockIdx&7==p (XCD-local);
//     per-XCD stream is 1.6MB instead of 12.8MB so the dirty edge_src slice
//     (0.8MB) survives in L2 and writebacks merge (R2: 74MB WRITE for 6.4MB).

#define SCAN_CHUNK 2048   // 256 threads x 8 elements
#define NPARTS 8

__global__ void bucket_kernel(const int* __restrict__ src, const int* __restrict__ dst,
                              int E, int np, int cap,
                              int* __restrict__ gcur,
                              int* __restrict__ psrc, int* __restrict__ pdst) {
    __shared__ int cnt[NPARTS], base[NPARTS], cur[NPARTS];
    int per = (E + gridDim.x - 1) / gridDim.x;
    int beg = blockIdx.x * per;
    int end = min(E, beg + per);
    if (threadIdx.x < NPARTS) cnt[threadIdx.x] = 0;
    __syncthreads();
    for (int e = beg + threadIdx.x; e < end; e += blockDim.x) {
        int p = (int)((unsigned)dst[e] / (unsigned)np);
        atomicAdd(&cnt[p], 1);
    }
    __syncthreads();
    if (threadIdx.x < NPARTS) {
        base[threadIdx.x] = atomicAdd(&gcur[threadIdx.x], cnt[threadIdx.x]);
        cur[threadIdx.x] = 0;
    }
    __syncthreads();
    for (int e = beg + threadIdx.x; e < end; e += blockDim.x) {
        int d = dst[e];
        int p = (int)((unsigned)d / (unsigned)np);
        int slot = atomicAdd(&cur[p], 1);
        int pos = p * cap + base[p] + slot;
        psrc[pos] = src[e];
        pdst[pos] = d;
    }
}

// Partitioned histogram over bucketed pairs: part = blockIdx&7 -> XCD-local atomics.
__global__ void degp_kernel(const int* __restrict__ pdst, const int* __restrict__ gcur,
                            int cap, int* __restrict__ deg) {
    int part = blockIdx.x & (NPARTS - 1);
    int cnt = gcur[part];
    int nchunks = gridDim.x >> 3;
    int chunk = blockIdx.x >> 3;
    int per = (cnt + nchunks - 1) / nchunks;
    int beg = chunk * per;
    int end = min(cnt, beg + per);
    const int* pd = pdst + (size_t)part * cap;
    for (int e = beg + threadIdx.x; e < end; e += blockDim.x)
        atomicAdd(&deg[pd[e]], 1);
}

__global__ void fillp_kernel(const int* __restrict__ psrc, const int* __restrict__ pdst,
                             const int* __restrict__ gcur, int cap,
                             int* __restrict__ cursor, int* __restrict__ edge_src) {
    int part = blockIdx.x & (NPARTS - 1);
    int cnt = gcur[part];
    int nchunks = gridDim.x >> 3;
    int chunk = blockIdx.x >> 3;
    int per = (cnt + nchunks - 1) / nchunks;
    int beg = chunk * per;
    int end = min(cnt, beg + per);
    const int* ps = psrc + (size_t)part * cap;
    const int* pd = pdst + (size_t)part * cap;
    for (int e = beg + threadIdx.x; e < end; e += blockDim.x) {
        int d = pd[e];
        int pos = atomicAdd(&cursor[d], 1);
        edge_src[pos] = ps[e];
    }
}

__global__ void scan_chunks(const int* __restrict__ deg, int N,
                            int* __restrict__ offs, int* __restrict__ blockSums) {
    __shared__ int lds[256];
    int b = blockIdx.x;
    int tid = threadIdx.x;
    int idx0 = b * SCAN_CHUNK + tid * 8;
    int v[8];
    int sum = 0;
#pragma unroll
    for (int i = 0; i < 8; ++i) {
        int idx = idx0 + i;
        int d = (idx < N) ? deg[idx] : 0;
        v[i] = d; sum += d;
    }
    lds[tid] = sum;
    __syncthreads();
    for (int s = 1; s < 256; s <<= 1) {
        int t = (tid >= s) ? lds[tid - s] : 0;
        __syncthreads();
        lds[tid] += t;
        __syncthreads();
    }
    int run = (tid == 0) ? 0 : lds[tid - 1];
    if (tid == 255) blockSums[b] = lds[255];
#pragma unroll
    for (int i = 0; i < 8; ++i) {
        int idx = idx0 + i;
        if (idx < N) offs[idx] = run;
        run += v[i];
    }
}

__global__ void scan_blocksums(int* __restrict__ blockSums, int nb,
                               int* __restrict__ offs, int N) {
    if (blockIdx.x == 0 && threadIdx.x == 0) {
        int run = 0;
        for (int b = 0; b < nb; ++b) { int t = blockSums[b]; blockSums[b] = run; run += t; }
        offs[N] = run;
    }
}

__global__ void add_offsets(int* __restrict__ offs, int* __restrict__ cursor,
                            const int* __restrict__ blockSums, int N) {
    int i = blockIdx.x * blockDim.x + threadIdx.x;
    if (i < N) {
        int o = offs[i] + blockSums[i / SCAN_CHUNK];
        offs[i] = o;
        cursor[i] = o;
    }
}

// One node row per 16 consecutive lanes; lane c owns float4 chunk c.
// FINAL=0: out = acc*inv (normalized mean).  FINAL=1: out = (xskip + acc*inv)*0.5.
template <int FINAL>
__launch_bounds__(256)
__global__ void agg_kernel(const float* __restrict__ xin,
                           const int* __restrict__ offs,
                           const int* __restrict__ edge_src,
                           const float* __restrict__ xskip,
                           float* __restrict__ outbuf, int N) {
    int t = blockIdx.x * blockDim.x + threadIdx.x;
    int n = t >> 4;
    int c = t & 15;
    if (n >= N) return;
    int beg = offs[n];
    int end = offs[n + 1];
    float ax = 0.f, ay = 0.f, az = 0.f, aw = 0.f;
    int k = beg;
    for (; k + 8 <= end; k += 8) {
        int s[8];
#pragma unroll
        for (int i = 0; i < 8; ++i) s[i] = edge_src[k + i];
#pragma unroll
        for (int i = 0; i < 8; ++i) {
            const float4 v = *reinterpret_cast<const float4*>(xin + ((size_t)s[i] << 6) + c * 4);
            ax += v.x; ay += v.y; az += v.z; aw += v.w;
        }
    }
    for (; k < end; ++k) {
        int s = edge_src[k];
        const float4 v = *reinterpret_cast<const float4*>(xin + ((size_t)s << 6) + c * 4);
        ax += v.x; ay += v.y; az += v.z; aw += v.w;
    }
    float inv = (end > beg) ? 1.0f / (float)(end - beg) : 0.0f;
    float4 r;
    if (FINAL) {
        const float4 xs = *reinterpret_cast<const float4*>(xskip + ((size_t)n << 6) + c * 4);
        r.x = (xs.x + ax * inv) * 0.5f;
        r.y = (xs.y + ay * inv) * 0.5f;
        r.z = (xs.z + az * inv) * 0.5f;
        r.w = (xs.w + aw * inv) * 0.5f;
    } else {
        r.x = ax * inv;
        r.y = ay * inv;
        r.z = az * inv;
        r.w = aw * inv;
    }
    *reinterpret_cast<float4*>(outbuf + ((size_t)n << 6) + c * 4) = r;
}

static inline size_t align_up(size_t x, size_t a) { return (x + a - 1) & ~(a - 1); }

extern "C" void kernel_launch(void* const* d_in, const int* in_sizes, int n_in,
                              void* d_out, int out_size, void* d_ws, size_t ws_size,
                              hipStream_t stream) {
    const float* feat = (const float*)d_in[0];
    const int*   src  = (const int*)d_in[1];
    const int*   dst  = (const int*)d_in[2];
    float* out = (float*)d_out;

    const int D = 64;
    int N = in_sizes[0] / D;   // 100000
    int E = in_sizes[1];       // 1600000
    int NB = (N + SCAN_CHUNK - 1) / SCAN_CHUNK;  // 49
    int np  = (N + NPARTS - 1) / NPARTS;         // 12500
    int cap = E / NPARTS + 8192;                 // per-part capacity with slack

    // workspace layout; pairs overlay buf_x (pairs dead before agg0 writes buf_x)
    char* ws = (char*)d_ws;
    size_t off = 0;
    float* buf_x = (float*)(ws + off); off = align_up(off + (size_t)N * D * sizeof(float), 256);
    int* deg     = (int*)(ws + off);   off += (size_t)N * sizeof(int);
    int* gcur    = (int*)(ws + off);   off = align_up(off + NPARTS * sizeof(int), 256);
    int* offs    = (int*)(ws + off);   off = align_up(off + (size_t)(N + 1) * sizeof(int), 256);
    int* cursor  = (int*)(ws + off);   off = align_up(off + (size_t)N * sizeof(int), 256);
    int* bsums   = (int*)(ws + off);   off = align_up(off + (size_t)NB * sizeof(int), 256);
    int* edge_src= (int*)(ws + off);   off = align_up(off + (size_t)E * sizeof(int), 256);
    int* psrc = (int*)buf_x;           // overlay
    int* pdst = psrc + (size_t)NPARTS * cap;
    (void)ws_size;

    // deg and gcur are adjacent: one memset clears both
    hipMemsetAsync(deg, 0, (size_t)N * sizeof(int) + NPARTS * sizeof(int), stream);

    const int BLK = 256;
    int grid_part = 2048;  // 256 chunks x 8 XCD parts
    int grid_n = (N + BLK - 1) / BLK;
    int grid_a = (N * 16 + BLK - 1) / BLK;

    bucket_kernel<<<grid_part, BLK, 0, stream>>>(src, dst, E, np, cap, gcur, psrc, pdst);
    degp_kernel<<<grid_part, BLK, 0, stream>>>(pdst, gcur, cap, deg);
    scan_chunks<<<NB, BLK, 0, stream>>>(deg, N, offs, bsums);
    scan_blocksums<<<1, 64, 0, stream>>>(bsums, NB, offs, N);
    add_offsets<<<grid_n, BLK, 0, stream>>>(offs, cursor, bsums, N);
    fillp_kernel<<<grid_part, BLK, 0, stream>>>(psrc, pdst, gcur, cap, cursor, edge_src);

    agg_kernel<0><<<grid_a, BLK, 0, stream>>>(feat, offs, edge_src, nullptr, buf_x, N);
    agg_kernel<1><<<grid_a, BLK, 0, stream>>>(buf_x, offs, edge_src, buf_x, out, N);
}